// Round 3
// baseline (133.873 us; speedup 1.0000x reference)
//
#include <hip/hip_runtime.h>

#define UNITS 256
#define NB 501               // num buckets
#define STEPF 0.05f
#define LBF -17.0f
#define UBF 8.0f
#define RESIDUEF -17.05f     // LB - STEP
#define LOG2E 1.4426950408889634f

#define WLO 208              // hot window idx [208,432) -> x in [-6.65, 4.55)
#define WSZ 224              // P(cold) ~ 2.7e-6 -> ~45 elements take global path
#define UPB 32               // units per block; LDS = 32*225*8 = 57600 B
                             // -> 2 blocks/CU even under a 128 KiB effective cap
#define PADF2 225            // LDS row stride in float2 (odd -> bank stagger)
#define THREADS 1024         // 16 waves; 2 blocks/CU, 32 waves/CU
#define ROWS_PB 1024         // grid = 8 unit-tiles * 64 row-tiles = 512 blocks
#define CHUNKS 8             // FULL prefetch: all 8 x-loads issued before the
                             // barrier. All loads precede all stores in issue
                             // order -> in-order vmcnt retirement means load
                             // waits can never block on slow HBM store retire
                             // (the round-2 ring interleaved L/S and serialized
                             // the per-wave memory pipeline on store latency).

// native vector type for nontemporal builtin (HIP float4 is a class type)
typedef float floatx4 __attribute__((ext_vector_type(4)));

// ---------------------------------------------------------------------------
// Kernel 1: full fused table -> d_ws (1.03 MB, L2/L3-resident).
//   w  = relu(v[u,j])
//   C  = STEP*excl_cumsum(w)[j] + RESIDUE + b[u] - j*STEP*w
//   store (C*log2e, w*log2e):  sigmoid = rcp(1 + exp2(-(C2 + t*w2))),
//   t = clamp(x)+17.05.  One wave per unit, 8 buckets/lane.
// ---------------------------------------------------------------------------
__global__ __launch_bounds__(256) void build_table_kernel(
    const float* __restrict__ v, const float* __restrict__ b,
    float2* __restrict__ gtab) {
  const int lane = threadIdx.x & 63;
  const int wave = threadIdx.x >> 6;
  const int u = blockIdx.x * 4 + wave;
  if (u >= UNITS) return;

  const float* vu = v + u * NB;
  float w[8], pref[8];
  float run = 0.0f;
#pragma unroll
  for (int k = 0; k < 8; ++k) {
    const int j = lane * 8 + k;
    const float wv = (j < NB) ? fmaxf(vu[j], 0.0f) : 0.0f;
    w[k] = wv;
    pref[k] = run;  // exclusive within-lane prefix
    run += wv;
  }
  float s = run;    // inclusive wave scan of per-lane sums
#pragma unroll
  for (int d = 1; d < 64; d <<= 1) {
    const float o = __shfl_up(s, d, 64);
    if (lane >= d) s += o;
  }
  const float base = s - run;  // exclusive lane base
  const float off = RESIDUEF + b[u];
#pragma unroll
  for (int k = 0; k < 8; ++k) {
    const int j = lane * 8 + k;
    if (j < NB) {
      const float C = STEPF * (base + pref[k]) + off - (float)j * STEPF * w[k];
      gtab[u * NB + j] = make_float2(C * LOG2E, w[k] * LOG2E);
    }
  }
}

// ---------------------------------------------------------------------------
// Kernel 2: stream x -> out.  Per block: 32 units x 1024 rows, 1024 threads.
// LDS: 32-unit x 224-bucket hot window, 57600 B -> 2 blocks/CU, 32 waves/CU.
// Pipeline shape: stage window + issue ALL 8 x-prefetches, one barrier (its
// vmcnt(0) drain absorbs the whole x latency ONCE), then a pure
// {4x ds_read_b64 -> VALU -> nontemporal store} loop with zero load waits.
// Stores are issued after every load -> never block a load wait (in-order
// vmcnt retirement).
// ---------------------------------------------------------------------------
__global__ __launch_bounds__(THREADS, 8) void iso_main_kernel(
    const float* __restrict__ x, const float2* __restrict__ gtab,
    float* __restrict__ out) {
  __shared__ float2 tab[UPB * PADF2];  // 57600 B

  const int bu = blockIdx.x & 7;            // unit tile 0..7 (UPB=32)
  const int bb = blockIdx.x >> 3;           // batch tile 0..63
  const int u0 = bu * UPB;
  const int tid = threadIdx.x;

  // ---- stage hot window: 32 threads per unit, 7 entries each (224/32) ----
  {
    const int ul = tid >> 5;                // unit 0..31
    const int jt = tid & 31;
    const float2* __restrict__ src = gtab + (u0 + ul) * NB + WLO;
#pragma unroll
    for (int r = 0; r < 7; ++r) {
      const int j = jt + r * 32;            // 32-thread groups read 256 B runs
      tab[ul * PADF2 + j] = src[j];
    }
  }

  // ---- full x prefetch: 8 chunk loads, all in flight before the barrier ----
  const int rowoff = tid >> 3;              // 0..127 within chunk
  const int col4 = tid & 7;                 // float4 col within 32-unit span
  const float4* __restrict__ x4 = reinterpret_cast<const float4*>(x);
  floatx4* __restrict__ o4 = reinterpret_cast<floatx4*>(out);
  const int g0 = (bb * ROWS_PB + rowoff) * (UNITS / 4) + bu * (UPB / 4) + col4;
  const int gstep = 128 * (UNITS / 4);      // 128 rows per chunk
  const int qbase = (col4 * 4) * PADF2;     // LDS base for this thread's units

  float4 xv[CHUNKS];
#pragma unroll
  for (int c = 0; c < CHUNKS; ++c) xv[c] = x4[g0 + c * gstep];

  __syncthreads();  // drains staging loads + x prefetch once; only barrier

  // ---- compute loop: no load waits, stores free-run behind ----
#pragma unroll
  for (int c = 0; c < CHUNKS; ++c) {
    const float4 cur = xv[c];
    const float xs[4] = {cur.x, cur.y, cur.z, cur.w};
    float os[4];
#pragma unroll
    for (int k = 0; k < 4; ++k) {
      const float xc = fminf(fmaxf(xs[k], LBF + 1e-9f), UBF - 1e-9f);
      const float t = xc - LBF + STEPF;     // xc + 17.05, in (0, 25.05)
      int idx = (int)(t * 20.0f);           // 1/STEP == 20 exactly
      const unsigned iw = (unsigned)(idx - WLO);
      float2 cw;
      if (iw < WSZ) {                       // hot path: one ds_read_b64
        cw = tab[qbase + k * PADF2 + (int)iw];
      } else {                              // ~2.7e-6 of elements
        idx = idx < 0 ? 0 : (idx > NB - 1 ? NB - 1 : idx);
        cw = gtab[(u0 + col4 * 4 + k) * NB + idx];
      }
      const float l2 = fmaf(t, cw.y, cw.x); // log2e * logit
      const float e = __builtin_amdgcn_exp2f(-l2);
      os[k] = __builtin_amdgcn_rcpf(1.0f + e);
    }
    // out is write-once / never re-read: non-temporal store keeps the 64 MB
    // output stream from evicting x + gtab lines in L2/L3.
    floatx4 ov;
    ov.x = os[0]; ov.y = os[1]; ov.z = os[2]; ov.w = os[3];
    __builtin_nontemporal_store(ov, &o4[g0 + c * gstep]);
  }
}

extern "C" void kernel_launch(void* const* d_in, const int* in_sizes, int n_in,
                              void* d_out, int out_size, void* d_ws,
                              size_t ws_size, hipStream_t stream) {
  const float* x = (const float*)d_in[0];   // (65536, 256)
  const float* v = (const float*)d_in[1];   // (256, 501)
  const float* b = (const float*)d_in[2];   // (256,)
  float* out = (float*)d_out;               // (65536, 256)
  float2* gtab = (float2*)d_ws;             // 256*501*8 B = 1.03 MB

  build_table_kernel<<<64, 256, 0, stream>>>(v, b, gtab);

  const int rows = out_size / UNITS;                  // 65536
  const int grid = (UNITS / UPB) * (rows / ROWS_PB);  // 8 * 64 = 512
  iso_main_kernel<<<grid, THREADS, 0, stream>>>(x, gtab, out);
}

// Round 4
// 132.413 us; speedup vs baseline: 1.0110x; 1.0110x over previous
//
#include <hip/hip_runtime.h>

#define UNITS 256
#define NB 501               // num buckets
#define STEPF 0.05f
#define LBF -17.0f
#define UBF 8.0f
#define RESIDUEF -17.05f     // LB - STEP
#define LOG2E 1.4426950408889634f

#define WLO 208              // hot window idx [208,432) -> x in [-6.65, 4.55)
#define WSZ 224              // P(cold) ~ 2.7e-6 -> ~45 elements take global path
#define UPB 32               // units per block; LDS = 32*225*8 = 57600 B
#define PADF2 225            // LDS row stride in float2 (odd -> bank stagger)
#define THREADS 1024         // 16 waves; 2 blocks/CU, 32 waves/CU (VGPR<=64)
#define ROWS_PB 1024         // grid = 8 unit-tiles * 64 row-tiles = 512 blocks
#define CHUNKS 8             // full prefetch, PINNED in VGPRs (see below)

// native vector type: usable with __builtin_nontemporal_store and as a
// 128-bit "v" inline-asm operand (HIP float4 is a class type; neither works)
typedef float floatx4 __attribute__((ext_vector_type(4)));

// ---------------------------------------------------------------------------
// Kernel 1: full fused table -> d_ws (1.03 MB, L2/L3-resident).
//   w  = relu(v[u,j])
//   C  = STEP*excl_cumsum(w)[j] + RESIDUE + b[u] - j*STEP*w
//   store (C*log2e, w*log2e):  sigmoid = rcp(1 + exp2(-(C2 + t*w2))),
//   t = clamp(x)+17.05.  One wave per unit, 8 buckets/lane.
// ---------------------------------------------------------------------------
__global__ __launch_bounds__(256) void build_table_kernel(
    const float* __restrict__ v, const float* __restrict__ b,
    float2* __restrict__ gtab) {
  const int lane = threadIdx.x & 63;
  const int wave = threadIdx.x >> 6;
  const int u = blockIdx.x * 4 + wave;
  if (u >= UNITS) return;

  const float* vu = v + u * NB;
  float w[8], pref[8];
  float run = 0.0f;
#pragma unroll
  for (int k = 0; k < 8; ++k) {
    const int j = lane * 8 + k;
    const float wv = (j < NB) ? fmaxf(vu[j], 0.0f) : 0.0f;
    w[k] = wv;
    pref[k] = run;  // exclusive within-lane prefix
    run += wv;
  }
  float s = run;    // inclusive wave scan of per-lane sums
#pragma unroll
  for (int d = 1; d < 64; d <<= 1) {
    const float o = __shfl_up(s, d, 64);
    if (lane >= d) s += o;
  }
  const float base = s - run;  // exclusive lane base
  const float off = RESIDUEF + b[u];
#pragma unroll
  for (int k = 0; k < 8; ++k) {
    const int j = lane * 8 + k;
    if (j < NB) {
      const float C = STEPF * (base + pref[k]) + off - (float)j * STEPF * w[k];
      gtab[u * NB + j] = make_float2(C * LOG2E, w[k] * LOG2E);
    }
  }
}

// ---------------------------------------------------------------------------
// Kernel 2: stream x -> out.  Per block: 32 units x 1024 rows, 1024 threads.
// LDS: 32-unit x 224-bucket hot window, 57600 B -> 2 blocks/CU, 32 waves/CU.
//
// ROUND-4 FIX: round 3's "full prefetch" was silently defeated -- VGPR_Count
// was 32, impossible with 8 resident float4, so LLVM had sunk the x-loads
// past __syncthreads back into the loop (legal: x is const __restrict__),
// recreating the load-behind-store vmcnt stall. Each xv[c] is now PINNED with
// asm volatile("" : "+v"(xv[c])) between the load loop and the barrier: the
// loads must complete before the barrier and stay in VGPRs. Compute loop is
// then pure {ds_read_b64 -> VALU -> nt-store}, no vmcnt waits until endpgm.
// Budget: 32 (xv) + ~20 temps <= 64 VGPR -> 8 waves/SIMD holds.
// ---------------------------------------------------------------------------
__global__ __launch_bounds__(THREADS, 8) void iso_main_kernel(
    const float* __restrict__ x, const float2* __restrict__ gtab,
    float* __restrict__ out) {
  __shared__ float2 tab[UPB * PADF2];  // 57600 B

  const int bu = blockIdx.x & 7;            // unit tile 0..7 (UPB=32)
  const int bb = blockIdx.x >> 3;           // batch tile 0..63
  const int u0 = bu * UPB;
  const int tid = threadIdx.x;

  // ---- stage hot window: 32 threads per unit, 7 entries each (224/32) ----
  {
    const int ul = tid >> 5;                // unit 0..31
    const int jt = tid & 31;
    const float2* __restrict__ src = gtab + (u0 + ul) * NB + WLO;
#pragma unroll
    for (int r = 0; r < 7; ++r) {
      const int j = jt + r * 32;            // 32-thread groups read 256 B runs
      tab[ul * PADF2 + j] = src[j];
    }
  }

  // ---- full x prefetch: 8 chunk loads, all in flight before the barrier ----
  const int rowoff = tid >> 3;              // 0..127 within chunk
  const int col4 = tid & 7;                 // float4 col within 32-unit span
  const floatx4* __restrict__ x4 = reinterpret_cast<const floatx4*>(x);
  floatx4* __restrict__ o4 = reinterpret_cast<floatx4*>(out);
  const int g0 = (bb * ROWS_PB + rowoff) * (UNITS / 4) + bu * (UPB / 4) + col4;
  const int gstep = 128 * (UNITS / 4);      // 128 rows per chunk
  const int qbase = (col4 * 4) * PADF2;     // LDS base for this thread's units

  floatx4 xv[CHUNKS];
#pragma unroll
  for (int c = 0; c < CHUNKS; ++c) xv[c] = x4[g0 + c * gstep];
  // Pin: force each loaded value to materialize in a VGPR HERE. Prevents the
  // register allocator from sinking the loads past the barrier (round-3 bug).
#pragma unroll
  for (int c = 0; c < CHUNKS; ++c) asm volatile("" : "+v"(xv[c]));

  __syncthreads();  // drains staging + (already-waited) x prefetch; only barrier

  // ---- compute loop: no load waits, stores free-run behind ----
#pragma unroll
  for (int c = 0; c < CHUNKS; ++c) {
    const floatx4 cur = xv[c];
    const float xs[4] = {cur.x, cur.y, cur.z, cur.w};
    float os[4];
#pragma unroll
    for (int k = 0; k < 4; ++k) {
      const float xc = fminf(fmaxf(xs[k], LBF + 1e-9f), UBF - 1e-9f);
      const float t = xc - LBF + STEPF;     // xc + 17.05, in (0, 25.05)
      int idx = (int)(t * 20.0f);           // 1/STEP == 20 exactly
      const unsigned iw = (unsigned)(idx - WLO);
      float2 cw;
      if (iw < WSZ) {                       // hot path: one ds_read_b64
        cw = tab[qbase + k * PADF2 + (int)iw];
      } else {                              // ~2.7e-6 of elements
        idx = idx < 0 ? 0 : (idx > NB - 1 ? NB - 1 : idx);
        cw = gtab[(u0 + col4 * 4 + k) * NB + idx];
      }
      const float l2 = fmaf(t, cw.y, cw.x); // log2e * logit
      const float e = __builtin_amdgcn_exp2f(-l2);
      os[k] = __builtin_amdgcn_rcpf(1.0f + e);
    }
    // out is write-once / never re-read: non-temporal store keeps the 64 MB
    // output stream from evicting x + gtab lines in L2/L3.
    floatx4 ov;
    ov.x = os[0]; ov.y = os[1]; ov.z = os[2]; ov.w = os[3];
    __builtin_nontemporal_store(ov, &o4[g0 + c * gstep]);
  }
}

extern "C" void kernel_launch(void* const* d_in, const int* in_sizes, int n_in,
                              void* d_out, int out_size, void* d_ws,
                              size_t ws_size, hipStream_t stream) {
  const float* x = (const float*)d_in[0];   // (65536, 256)
  const float* v = (const float*)d_in[1];   // (256, 501)
  const float* b = (const float*)d_in[2];   // (256,)
  float* out = (float*)d_out;               // (65536, 256)
  float2* gtab = (float2*)d_ws;             // 256*501*8 B = 1.03 MB

  build_table_kernel<<<64, 256, 0, stream>>>(v, b, gtab);

  const int rows = out_size / UNITS;                  // 65536
  const int grid = (UNITS / UPB) * (rows / ROWS_PB);  // 8 * 64 = 512
  iso_main_kernel<<<grid, THREADS, 0, stream>>>(x, gtab, out);
}